// Round 1
// baseline (960.253 us; speedup 1.0000x reference)
//
#include <hip/hip_runtime.h>
#include <hip/hip_bf16.h>

#define NPTS 16384
#define CDIM 256
#define HEADS 8
#define DHEAD 64
#define KNBR 8
#define HIDD 512
#define OUTD 64
#define NEMB 64
#define RHIDD 16

__device__ __forceinline__ float gelu_tanh(float v) {
    float v3 = v * v * v;
    return 0.5f * v * (1.0f + tanhf(0.79788456080286535588f * (v + 0.044715f * v3)));
}

// ---------------------------------------------------------------------------
// Tiled fp32 GEMM  C[M,Ncol] = A[M,Kd] @ B[Kd,Ncol]  with fused epilogues.
// BM=BN=128, BK=16, 256 threads, 8x8 per thread.
// EPI 0: plain
// EPI 1: v = tanh(alpha*(acc + res[row,col])) * gamma[col] + beta[col]
// EPI 2: v = gelu(acc + bias[col])
// EPI 3: v = tanh(gelu(acc + bias[col]))
// ---------------------------------------------------------------------------
#define BM 128
#define BN 128
#define BK 16

template <int EPI>
__launch_bounds__(256)
__global__ void gemm_epi(const float* __restrict__ A, const float* __restrict__ B,
                         float* __restrict__ C,
                         const float* __restrict__ bias,
                         const float* __restrict__ res,
                         const float* __restrict__ alpha,
                         const float* __restrict__ gamma,
                         const float* __restrict__ beta,
                         int M, int Kd, int Ncol) {
    __shared__ float As[BK][BM + 4];
    __shared__ float Bs[BK][BN + 4];

    const int tid = threadIdx.x;
    const int tx = tid & 15;        // 0..15 -> col groups of 8
    const int ty = tid >> 4;        // 0..15 -> row groups of 8
    const int m0 = blockIdx.y * BM;
    const int n0 = blockIdx.x * BN;

    const int arow = tid >> 2;            // 0..63
    const int acol = (tid & 3) * 4;       // 0,4,8,12
    const int brow = tid >> 5;            // 0..7
    const int bcol = (tid & 31) * 4;      // 0..124

    float acc[8][8] = {};

    for (int k0 = 0; k0 < Kd; k0 += BK) {
        // ---- load A tile (transposed into As[k][m]) ----
        #pragma unroll
        for (int r = 0; r < 2; ++r) {
            int row = arow + r * 64;
            int kk = k0 + acol;
            float4 va = {0.f, 0.f, 0.f, 0.f};
            const float* ap = A + (size_t)(m0 + row) * Kd + kk;
            if (kk + 3 < Kd) {
                va = *(const float4*)ap;
            } else {
                if (kk + 0 < Kd) va.x = ap[0];
                if (kk + 1 < Kd) va.y = ap[1];
                if (kk + 2 < Kd) va.z = ap[2];
                if (kk + 3 < Kd) va.w = ap[3];
            }
            As[acol + 0][row] = va.x;
            As[acol + 1][row] = va.y;
            As[acol + 2][row] = va.z;
            As[acol + 3][row] = va.w;
        }
        // ---- load B tile ----
        #pragma unroll
        for (int r = 0; r < 2; ++r) {
            int krow = k0 + brow + r * 8;
            int nn = n0 + bcol;
            float4 vb = {0.f, 0.f, 0.f, 0.f};
            if (krow < Kd && nn < Ncol) {
                vb = *(const float4*)(B + (size_t)krow * Ncol + nn);
            }
            *(float4*)&Bs[brow + r * 8][bcol] = vb;
        }
        __syncthreads();

        #pragma unroll
        for (int kk = 0; kk < BK; ++kk) {
            float4 a0 = *(const float4*)&As[kk][ty * 8];
            float4 a1 = *(const float4*)&As[kk][ty * 8 + 4];
            float4 b0 = *(const float4*)&Bs[kk][tx * 8];
            float4 b1 = *(const float4*)&Bs[kk][tx * 8 + 4];
            float ra[8] = {a0.x, a0.y, a0.z, a0.w, a1.x, a1.y, a1.z, a1.w};
            float rb[8] = {b0.x, b0.y, b0.z, b0.w, b1.x, b1.y, b1.z, b1.w};
            #pragma unroll
            for (int i = 0; i < 8; ++i)
                #pragma unroll
                for (int j = 0; j < 8; ++j)
                    acc[i][j] += ra[i] * rb[j];
        }
        __syncthreads();
    }

    const float alp = (EPI == 1) ? alpha[0] : 0.f;

    #pragma unroll
    for (int i = 0; i < 8; ++i) {
        int row = m0 + ty * 8 + i;
        #pragma unroll
        for (int j = 0; j < 8; ++j) {
            int col = n0 + tx * 8 + j;
            if (col < Ncol) {
                float v = acc[i][j];
                if (EPI == 1) {
                    v += res[(size_t)row * Ncol + col];
                    v = tanhf(alp * v) * gamma[col] + beta[col];
                } else if (EPI == 2) {
                    v = gelu_tanh(v + bias[col]);
                } else if (EPI == 3) {
                    v = tanhf(gelu_tanh(v + bias[col]));
                }
                C[(size_t)row * Ncol + col] = v;
            }
        }
    }
}

// ---------------------------------------------------------------------------
// gate GEMM: G[N,8] = x[N,256] @ w_gate[256,8]; one thread per (n,h)
// ---------------------------------------------------------------------------
__global__ void gate_kernel(const float* __restrict__ x, const float* __restrict__ w_gate,
                            float* __restrict__ G) {
    int idx = blockIdx.x * 256 + threadIdx.x;   // n*8 + h
    if (idx >= NPTS * HEADS) return;
    int n = idx >> 3;
    int h = idx & 7;
    const float* xr = x + (size_t)n * CDIM;
    float s = 0.f;
    #pragma unroll 8
    for (int i = 0; i < CDIM; ++i) s += xr[i] * w_gate[i * 8 + h];
    G[idx] = s;
}

// ---------------------------------------------------------------------------
// Attention: one wave (64 lanes) per node. lane = h*8 + c.
// Phase 1: per-lane partial dots over its 8-float chunk, butterfly over c.
// Phase 2: out0 chunk lane*8..+7 (same head), coalesced V loads.
// Writes att[n, 0:512] = out0, att[n, 512+h] = vecnorm.
// ---------------------------------------------------------------------------
__launch_bounds__(256)
__global__ void attn_kernel(const float* __restrict__ Q, const float* __restrict__ Km,
                            const float* __restrict__ Vm, const float* __restrict__ G,
                            const float* __restrict__ coors, const int* __restrict__ nbr,
                            const float* __restrict__ Wr1, const float* __restrict__ br1,
                            const float* __restrict__ Wr2, const float* __restrict__ br2,
                            float* __restrict__ att) {
    __shared__ float unitL[4][8][3];
    __shared__ float distL[4][8];
    __shared__ float radH[4][8][16];

    const int tid = threadIdx.x;
    const int w = tid >> 6;
    const int lane = tid & 63;
    const int n = blockIdx.x * 4 + w;
    const int h = lane >> 3;
    const int c = lane & 7;

    int jreg[KNBR];
    #pragma unroll
    for (int k = 0; k < KNBR; ++k) jreg[k] = nbr[(size_t)n * KNBR + k];

    // distances / unit vectors (lanes 0..7, one neighbor each)
    if (lane < KNBR) {
        int jj = jreg[lane];
        float rx = coors[(size_t)jj * 3 + 0] - coors[(size_t)n * 3 + 0];
        float ry = coors[(size_t)jj * 3 + 1] - coors[(size_t)n * 3 + 1];
        float rz = coors[(size_t)jj * 3 + 2] - coors[(size_t)n * 3 + 2];
        float d = sqrtf(rx * rx + ry * ry + rz * rz + 1e-8f);
        float inv = 1.0f / d;
        distL[w][lane] = d;
        unitL[w][lane][0] = rx * inv;
        unitL[w][lane][1] = ry * inv;
        unitL[w][lane][2] = rz * inv;
    }

    // phase 1: q . k partial dots
    const float4* qp = (const float4*)(Q + (size_t)n * 512 + lane * 8);
    float4 q0 = qp[0], q1 = qp[1];
    float p[KNBR];
    #pragma unroll
    for (int k = 0; k < KNBR; ++k) {
        const float4* kp = (const float4*)(Km + (size_t)jreg[k] * 512 + lane * 8);
        float4 k0 = kp[0], k1 = kp[1];
        p[k] = q0.x * k0.x + q0.y * k0.y + q0.z * k0.z + q0.w * k0.w
             + q1.x * k1.x + q1.y * k1.y + q1.z * k1.z + q1.w * k1.w;
    }
    #pragma unroll
    for (int m = 1; m <= 4; m <<= 1) {
        #pragma unroll
        for (int k = 0; k < KNBR; ++k) p[k] += __shfl_xor(p[k], m, 64);
    }
    __syncthreads();

    // radial hidden: 128 distinct (k,i) values, 2 per lane
    #pragma unroll
    for (int r = 0; r < 2; ++r) {
        int idx = lane + r * 64;
        int k = idx >> 4, i = idx & 15;
        float hv = distL[w][k] * Wr1[i] + br1[i];
        radH[w][k][i] = gelu_tanh(hv);
    }
    __syncthreads();

    // logits + mask + softmax over K (all in-lane for this head)
    float lg[KNBR];
    float b2 = br2[h];
    #pragma unroll
    for (int k = 0; k < KNBR; ++k) {
        float r = b2;
        #pragma unroll
        for (int i = 0; i < RHIDD; ++i) r += radH[w][k][i] * Wr2[i * HEADS + h];
        lg[k] = p[k] * 0.125f + r;
        if (!(distL[w][k] <= 10.0f)) lg[k] = -1e9f;
    }
    float mx = lg[0];
    #pragma unroll
    for (int k = 1; k < KNBR; ++k) mx = fmaxf(mx, lg[k]);
    float a[KNBR];
    float s = 0.f;
    #pragma unroll
    for (int k = 0; k < KNBR; ++k) { a[k] = expf(lg[k] - mx); s += a[k]; }
    float is = 1.0f / s;
    #pragma unroll
    for (int k = 0; k < KNBR; ++k) a[k] *= is;

    // degree-1 output: vec / vecnorm
    float vx = 0.f, vy = 0.f, vz = 0.f;
    #pragma unroll
    for (int k = 0; k < KNBR; ++k) {
        float g = G[(size_t)jreg[k] * HEADS + h];
        float ag = a[k] * g;
        vx += ag * unitL[w][k][0];
        vy += ag * unitL[w][k][1];
        vz += ag * unitL[w][k][2];
    }
    float vn = sqrtf(vx * vx + vy * vy + vz * vz + 1e-8f);
    if (c == 0) att[(size_t)n * 520 + 512 + h] = vn;

    // phase 2: out0 = attn . V   (coalesced chunk lane*8..+7, same head)
    float4 o0 = {0.f, 0.f, 0.f, 0.f}, o1 = {0.f, 0.f, 0.f, 0.f};
    #pragma unroll
    for (int k = 0; k < KNBR; ++k) {
        const float4* vp = (const float4*)(Vm + (size_t)jreg[k] * 512 + lane * 8);
        float4 v0 = vp[0], v1 = vp[1];
        float ak = a[k];
        o0.x += ak * v0.x; o0.y += ak * v0.y; o0.z += ak * v0.z; o0.w += ak * v0.w;
        o1.x += ak * v1.x; o1.y += ak * v1.y; o1.z += ak * v1.z; o1.w += ak * v1.w;
    }
    float4* op = (float4*)(att + (size_t)n * 520 + lane * 8);
    op[0] = o0;
    op[1] = o1;
}

// ---------------------------------------------------------------------------
// h2 = DynamicTanh(concat(h, x[:, :20]))   -> [N, 532]
// ---------------------------------------------------------------------------
__global__ void h2_kernel(const float* __restrict__ h, const float* __restrict__ x,
                          const float* __restrict__ alpha2, const float* __restrict__ gamma2,
                          const float* __restrict__ beta2, float* __restrict__ h2) {
    int idx = blockIdx.x * 256 + threadIdx.x;
    if (idx >= NPTS * 532) return;
    int n = idx / 532;
    int cidx = idx - n * 532;
    float v = (cidx < HIDD) ? h[(size_t)n * HIDD + cidx]
                            : x[(size_t)n * CDIM + (cidx - HIDD)];
    h2[idx] = tanhf(alpha2[0] * v) * gamma2[cidx] + beta2[cidx];
}

// ---------------------------------------------------------------------------
// VQ: one wave per node (lane = codebook entry). Writes zq rows to out and
// per-block squared-error partials (deterministic, no atomics).
// ---------------------------------------------------------------------------
__launch_bounds__(256)
__global__ void vq_kernel(const float* __restrict__ z, const float* __restrict__ cb,
                          float* __restrict__ out, float* __restrict__ partials) {
    __shared__ float cbL[NEMB][65];
    __shared__ float zL[4][OUTD];
    __shared__ float psum[4];

    const int tid = threadIdx.x;
    // stage codebook (4096 floats) into LDS, padded stride 65
    for (int i = tid; i < NEMB * OUTD / 4; i += 256) {
        float4 v = ((const float4*)cb)[i];
        int e = (i * 4) >> 6;
        int c0 = (i * 4) & 63;
        cbL[e][c0 + 0] = v.x; cbL[e][c0 + 1] = v.y;
        cbL[e][c0 + 2] = v.z; cbL[e][c0 + 3] = v.w;
    }
    const int w = tid >> 6;
    const int lane = tid & 63;
    const int n = blockIdx.x * 4 + w;
    zL[w][lane] = z[(size_t)n * OUTD + lane];
    __syncthreads();

    // lane e: score = ||cb_e||^2 - 2 z.cb_e   (||z||^2 shift doesn't move argmin)
    float dot = 0.f, cc = 0.f;
    #pragma unroll
    for (int i = 0; i < OUTD; ++i) {
        float cv = cbL[lane][i];
        dot += zL[w][i] * cv;
        cc += cv * cv;
    }
    float best = cc - 2.f * dot;
    int bidx = lane;
    #pragma unroll
    for (int m = 1; m < 64; m <<= 1) {
        float ob = __shfl_xor(best, m, 64);
        int oi = __shfl_xor(bidx, m, 64);
        if (ob < best || (ob == best && oi < bidx)) { best = ob; bidx = oi; }
    }
    float zq = cbL[bidx][lane];
    out[(size_t)n * OUTD + lane] = zq;
    float diff = zL[w][lane] - zq;
    float sq = diff * diff;
    #pragma unroll
    for (int m = 1; m < 64; m <<= 1) sq += __shfl_xor(sq, m, 64);
    if (lane == 0) psum[w] = sq;
    __syncthreads();
    if (tid == 0) partials[blockIdx.x] = psum[0] + psum[1] + psum[2] + psum[3];
}

__global__ void vq_reduce(const float* __restrict__ partials, float* __restrict__ out) {
    __shared__ float s[256];
    int tid = threadIdx.x;
    float acc = 0.f;
    for (int i = tid; i < NPTS / 4; i += 256) acc += partials[i];
    s[tid] = acc;
    __syncthreads();
    for (int st = 128; st > 0; st >>= 1) {
        if (tid < st) s[tid] += s[tid + st];
        __syncthreads();
    }
    if (tid == 0) out[0] = 0.25f * s[0] / ((float)NPTS * (float)OUTD);
}

// ---------------------------------------------------------------------------
extern "C" void kernel_launch(void* const* d_in, const int* in_sizes, int n_in,
                              void* d_out, int out_size, void* d_ws, size_t ws_size,
                              hipStream_t stream) {
    const float* x      = (const float*)d_in[0];
    const float* coors  = (const float*)d_in[1];
    const int*   nbr    = (const int*)  d_in[2];
    const float* Wq     = (const float*)d_in[3];
    const float* Wk     = (const float*)d_in[4];
    const float* Wv     = (const float*)d_in[5];
    const float* w_gate = (const float*)d_in[6];
    const float* Wr1    = (const float*)d_in[7];
    const float* br1    = (const float*)d_in[8];
    const float* Wr2    = (const float*)d_in[9];
    const float* br2    = (const float*)d_in[10];
    const float* Wo     = (const float*)d_in[11];
    const float* alpha1 = (const float*)d_in[12];
    const float* gamma1 = (const float*)d_in[13];
    const float* beta1  = (const float*)d_in[14];
    const float* Wlin   = (const float*)d_in[15];
    const float* blin   = (const float*)d_in[16];
    const float* alpha2 = (const float*)d_in[17];
    const float* gamma2 = (const float*)d_in[18];
    const float* beta2  = (const float*)d_in[19];
    const float* Wout   = (const float*)d_in[20];
    const float* bout   = (const float*)d_in[21];
    const float* cb     = (const float*)d_in[22];

    float* ws = (float*)d_ws;
    const size_t N = NPTS;
    float* Q    = ws;                       // N*512
    float* Km   = Q   + N * 512;            // N*512
    float* Vm   = Km  + N * 512;            // N*512
    float* G    = Vm  + N * 512;            // N*8
    float* att  = G   + N * 8;              // N*544 region (rows of 520 used)
    float* part = att + N * 544;            // N/4
    // aliases (lifetimes don't overlap):
    float* h1 = Q;     // N*256
    float* hh = Km;    // N*512
    float* h2 = att;   // N*532
    float* z  = Vm;    // N*64

    float* outZ    = (float*)d_out;          // N*64
    float* outLoss = outZ + N * OUTD;        // 1

    dim3 blk(256);

    // QKV projections
    gemm_epi<0><<<dim3(4, 128), blk, 0, stream>>>(x, Wq, Q,  nullptr, nullptr, nullptr, nullptr, nullptr, NPTS, 256, 512);
    gemm_epi<0><<<dim3(4, 128), blk, 0, stream>>>(x, Wk, Km, nullptr, nullptr, nullptr, nullptr, nullptr, NPTS, 256, 512);
    gemm_epi<0><<<dim3(4, 128), blk, 0, stream>>>(x, Wv, Vm, nullptr, nullptr, nullptr, nullptr, nullptr, NPTS, 256, 512);
    gate_kernel<<<dim3(NPTS * HEADS / 256), blk, 0, stream>>>(x, w_gate, G);

    // SE(3) sparse-neighbor attention
    attn_kernel<<<dim3(NPTS / 4), blk, 0, stream>>>(Q, Km, Vm, G, coors, nbr,
                                                    Wr1, br1, Wr2, br2, att);

    // se3_out = x + att@Wo; h1 = DynTanh(se3_out)
    gemm_epi<1><<<dim3(2, 128), blk, 0, stream>>>(att, Wo, h1, nullptr, x, alpha1, gamma1, beta1, NPTS, 520, 256);
    // h = gelu(h1@Wlin + blin)
    gemm_epi<2><<<dim3(4, 128), blk, 0, stream>>>(h1, Wlin, hh, blin, nullptr, nullptr, nullptr, nullptr, NPTS, 256, 512);
    // h2 = DynTanh(concat(h, x[:, :20]))
    h2_kernel<<<dim3((NPTS * 532 + 255) / 256), blk, 0, stream>>>(hh, x, alpha2, gamma2, beta2, h2);
    // z = tanh(gelu(h2@Wout + bout))
    gemm_epi<3><<<dim3(1, 128), blk, 0, stream>>>(h2, Wout, z, bout, nullptr, nullptr, nullptr, nullptr, NPTS, 532, 64);

    // VQ
    vq_kernel<<<dim3(NPTS / 4), blk, 0, stream>>>(z, cb, outZ, part);
    vq_reduce<<<dim3(1), blk, 0, stream>>>(part, outLoss);
}

// Round 2
// 453.033 us; speedup vs baseline: 2.1196x; 2.1196x over previous
//
#include <hip/hip_runtime.h>
#include <hip/hip_bf16.h>
#include <stdint.h>

#define NPTS 16384
#define CDIM 256
#define HEADS 8
#define KNBR 8
#define HIDD 512
#define OUTD 64
#define NEMB 64
#define RHIDD 16

typedef _Float16 half8 __attribute__((ext_vector_type(8)));
typedef float f32x4 __attribute__((ext_vector_type(4)));

__device__ __forceinline__ float gelu_tanh(float v) {
    float v3 = v * v * v;
    return 0.5f * v * (1.0f + tanhf(0.79788456080286535588f * (v + 0.044715f * v3)));
}

__device__ __forceinline__ void gload16(const void* g, void* l) {
    __builtin_amdgcn_global_load_lds((const __attribute__((address_space(1))) void*)g,
                                     (__attribute__((address_space(3))) void*)l, 16, 0, 0);
}

// ---------------------------------------------------------------------------
// Split-fp16 MFMA GEMM.  C[M,*] = A[M,K] @ B[K,*] computed as
// Ahi*Bhi + Ahi*Blo + Alo*Bhi over K' = 3*Kpad (fp32-grade accuracy).
// A2: [M][2*Kpad] halfs = [hi|lo].  B2: [Ncol][2*Kpad] halfs = W^T split [hi|lo].
// 128x128 tile, 4 waves (2x2), each wave 4x4 frags of 16x16x32 f16 MFMA.
// LDS: A tile [128 rows][64 k] halfs + B^T tile, XOR-swizzled (T2):
//   phys_byte(row,b) = row*128 + (b ^ ((row&7)<<4))
// global_load_lds writes linearly -> global source pre-swizzled (rule #21).
// EPI 0: fp32 store (ldc)           EPI 1: +res, DynTanh, split-fp16 out (ld 512)
// EPI 2: gelu(+bias), fp32 (ldc)    EPI 3: tanh(gelu(+bias)), fp32 ld 64, col<64
// ---------------------------------------------------------------------------
template <int EPI>
__launch_bounds__(256)
__global__ void gemm_split(const _Float16* __restrict__ A2, const _Float16* __restrict__ B2,
                           int Kpad, int KT,
                           void* __restrict__ Cout, int ldc,
                           const float* __restrict__ bias,
                           const float* __restrict__ res,
                           const float* __restrict__ alphap,
                           const float* __restrict__ gamma,
                           const float* __restrict__ beta) {
    __shared__ __align__(16) char lds[32768];

    const int tid = threadIdx.x;
    const int l = tid & 63, w = tid >> 6;
    const int g = l >> 4, r = l & 15;
    const int wr = w >> 1, wc = w & 1;
    const int m0 = blockIdx.y * 128;
    const int n0 = blockIdx.x * 128;
    const int ldA = 2 * Kpad;
    const int srow = l >> 3;                       // 0..7 (row within 1KB chunk)
    const int scol = ((l & 7) ^ srow) << 3;        // pre-swizzled half-col offset
    const int swz = (r & 7) << 4;                  // ds_read byte XOR
    const int aBase = (wr * 64 + r) * 128;
    const int bBase = 16384 + (wc * 64 + r) * 128;

    f32x4 acc[4][4] = {};

    for (int kt = 0; kt < KT; ++kt) {
        int k0 = kt * 64;
        int term = (k0 >= Kpad) ? ((k0 >= 2 * Kpad) ? 2 : 1) : 0;
        int kk0 = k0 - term * Kpad;
        int srcA = (term < 2) ? kk0 : (Kpad + kk0);       // A terms: hi,hi,lo
        int srcB = (term == 1) ? (Kpad + kk0) : kk0;      // B terms: hi,lo,hi
        const _Float16* aS = A2 + (size_t)m0 * ldA + srcA + scol;
        const _Float16* bS = B2 + (size_t)n0 * ldA + srcB + scol;
        #pragma unroll
        for (int cc = 0; cc < 4; ++cc) {
            int c = w * 4 + cc;                    // 1KB chunk id (wave-uniform)
            int row = c * 8 + srow;
            gload16(aS + (size_t)row * ldA, lds + c * 1024);
            gload16(bS + (size_t)row * ldA, lds + 16384 + c * 1024);
        }
        __syncthreads();
        #pragma unroll
        for (int kb = 0; kb < 2; ++kb) {
            int ko = ((kb << 6) | (g << 4)) ^ swz;
            half8 af[4], bf[4];
            #pragma unroll
            for (int i = 0; i < 4; ++i) af[i] = *(const half8*)(lds + aBase + i * 2048 + ko);
            #pragma unroll
            for (int j = 0; j < 4; ++j) bf[j] = *(const half8*)(lds + bBase + j * 2048 + ko);
            #pragma unroll
            for (int i = 0; i < 4; ++i)
                #pragma unroll
                for (int j = 0; j < 4; ++j)
                    acc[i][j] = __builtin_amdgcn_mfma_f32_16x16x32_f16(af[i], bf[j], acc[i][j], 0, 0, 0);
        }
        __syncthreads();
    }

    const float alp = (EPI == 1) ? alphap[0] : 0.f;
    #pragma unroll
    for (int i = 0; i < 4; ++i) {
        #pragma unroll
        for (int j = 0; j < 4; ++j) {
            const int gcol = n0 + wc * 64 + j * 16 + r;
            #pragma unroll
            for (int q = 0; q < 4; ++q) {
                const int row = m0 + wr * 64 + i * 16 + g * 4 + q;
                float v = acc[i][j][q];
                if (EPI == 0) {
                    ((float*)Cout)[(size_t)row * ldc + gcol] = v;
                } else if (EPI == 1) {
                    v += res[(size_t)row * CDIM + gcol];
                    v = tanhf(alp * v) * gamma[gcol] + beta[gcol];
                    _Float16 hi = (_Float16)v;
                    _Float16 lo = (_Float16)(v - (float)hi);
                    _Float16* H = (_Float16*)Cout;
                    H[(size_t)row * 512 + gcol] = hi;
                    H[(size_t)row * 512 + 256 + gcol] = lo;
                } else if (EPI == 2) {
                    v = gelu_tanh(v + bias[gcol]);
                    ((float*)Cout)[(size_t)row * ldc + gcol] = v;
                } else {
                    if (gcol < OUTD) {
                        v = tanhf(gelu_tanh(v + bias[gcol]));
                        ((float*)Cout)[(size_t)row * OUTD + gcol] = v;
                    }
                }
            }
        }
    }
}

// ---------------------------------------------------------------------------
// fp32 -> split fp16 [hi|lo] conversions
// ---------------------------------------------------------------------------
__global__ void x_split(const float* __restrict__ x, _Float16* __restrict__ x2) {
    int idx = blockIdx.x * 256 + threadIdx.x;      // n*256 + c
    if (idx >= NPTS * CDIM) return;
    int n = idx >> 8, c = idx & 255;
    float v = x[idx];
    _Float16 hi = (_Float16)v, lo = (_Float16)(v - (float)hi);
    x2[(size_t)n * 512 + c] = hi;
    x2[(size_t)n * 512 + 256 + c] = lo;
}

// combined QKV weight: out[j][k] over j in [0,1536)
__global__ void wqkv_split(const float* __restrict__ Wq, const float* __restrict__ Wk,
                           const float* __restrict__ Wv, _Float16* __restrict__ dst) {
    int idx = blockIdx.x * 256 + threadIdx.x;      // j*256 + k
    if (idx >= 1536 * 256) return;
    int j = idx >> 8, k = idx & 255;
    int jm = j & 511;
    const float* W = (j < 512) ? Wq : (j < 1024) ? Wk : Wv;
    float v = W[(size_t)k * 512 + jm];
    _Float16 hi = (_Float16)v, lo = (_Float16)(v - (float)hi);
    dst[(size_t)j * 512 + k] = hi;
    dst[(size_t)j * 512 + 256 + k] = lo;
}

// generic W[K][Ncol] -> dst[NP][2*KP] transposed split with zero pads
__global__ void wT_split(const float* __restrict__ W, _Float16* __restrict__ dst,
                         int K, int Ncol, int KP, int NP) {
    int idx = blockIdx.x * 256 + threadIdx.x;      // j*KP + k
    if (idx >= NP * KP) return;
    int j = idx / KP, k = idx - j * KP;
    float v = (j < Ncol && k < K) ? W[(size_t)k * Ncol + j] : 0.f;
    _Float16 hi = (_Float16)v, lo = (_Float16)(v - (float)hi);
    dst[(size_t)j * 2 * KP + k] = hi;
    dst[(size_t)j * 2 * KP + KP + k] = lo;
}

// ---------------------------------------------------------------------------
// gate GEMM: G[N,8] = x[N,256] @ w_gate[256,8]
// ---------------------------------------------------------------------------
__global__ void gate_kernel(const float* __restrict__ x, const float* __restrict__ w_gate,
                            float* __restrict__ G) {
    int idx = blockIdx.x * 256 + threadIdx.x;
    if (idx >= NPTS * HEADS) return;
    int n = idx >> 3;
    int h = idx & 7;
    const float* xr = x + (size_t)n * CDIM;
    float s = 0.f;
    #pragma unroll 8
    for (int i = 0; i < CDIM; ++i) s += xr[i] * w_gate[i * 8 + h];
    G[idx] = s;
}

// ---------------------------------------------------------------------------
// Attention: one wave per node, QKV packed [N][1536] fp32 (Q|K|V).
// Writes att2 [N][1152] split fp16: cols 0..511 out0, 512..519 vecnorm,
// 520..575 zero; hi block then lo block at +576.
// ---------------------------------------------------------------------------
__launch_bounds__(256)
__global__ void attn_kernel(const float* __restrict__ QKV, const float* __restrict__ G,
                            const float* __restrict__ coors, const int* __restrict__ nbr,
                            const float* __restrict__ Wr1, const float* __restrict__ br1,
                            const float* __restrict__ Wr2, const float* __restrict__ br2,
                            _Float16* __restrict__ att2) {
    __shared__ float unitL[4][8][3];
    __shared__ float distL[4][8];
    __shared__ float radH[4][8][16];

    const int tid = threadIdx.x;
    const int w = tid >> 6;
    const int lane = tid & 63;
    const int n = blockIdx.x * 4 + w;
    const int h = lane >> 3;
    const int c = lane & 7;

    int jreg[KNBR];
    #pragma unroll
    for (int k = 0; k < KNBR; ++k) jreg[k] = nbr[(size_t)n * KNBR + k];

    if (lane < KNBR) {
        int jj = jreg[lane];
        float rx = coors[(size_t)jj * 3 + 0] - coors[(size_t)n * 3 + 0];
        float ry = coors[(size_t)jj * 3 + 1] - coors[(size_t)n * 3 + 1];
        float rz = coors[(size_t)jj * 3 + 2] - coors[(size_t)n * 3 + 2];
        float d = sqrtf(rx * rx + ry * ry + rz * rz + 1e-8f);
        float inv = 1.0f / d;
        distL[w][lane] = d;
        unitL[w][lane][0] = rx * inv;
        unitL[w][lane][1] = ry * inv;
        unitL[w][lane][2] = rz * inv;
    }

    const float4* qp = (const float4*)(QKV + (size_t)n * 1536 + lane * 8);
    float4 q0 = qp[0], q1 = qp[1];
    float p[KNBR];
    #pragma unroll
    for (int k = 0; k < KNBR; ++k) {
        const float4* kp = (const float4*)(QKV + (size_t)jreg[k] * 1536 + 512 + lane * 8);
        float4 k0 = kp[0], k1 = kp[1];
        p[k] = q0.x * k0.x + q0.y * k0.y + q0.z * k0.z + q0.w * k0.w
             + q1.x * k1.x + q1.y * k1.y + q1.z * k1.z + q1.w * k1.w;
    }
    #pragma unroll
    for (int m = 1; m <= 4; m <<= 1) {
        #pragma unroll
        for (int k = 0; k < KNBR; ++k) p[k] += __shfl_xor(p[k], m, 64);
    }
    __syncthreads();

    #pragma unroll
    for (int rr = 0; rr < 2; ++rr) {
        int idx = lane + rr * 64;
        int k = idx >> 4, i = idx & 15;
        float hv = distL[w][k] * Wr1[i] + br1[i];
        radH[w][k][i] = gelu_tanh(hv);
    }
    __syncthreads();

    float lg[KNBR];
    float b2 = br2[h];
    #pragma unroll
    for (int k = 0; k < KNBR; ++k) {
        float rad = b2;
        #pragma unroll
        for (int i = 0; i < RHIDD; ++i) rad += radH[w][k][i] * Wr2[i * HEADS + h];
        lg[k] = p[k] * 0.125f + rad;
        if (!(distL[w][k] <= 10.0f)) lg[k] = -1e9f;
    }
    float mx = lg[0];
    #pragma unroll
    for (int k = 1; k < KNBR; ++k) mx = fmaxf(mx, lg[k]);
    float a[KNBR];
    float s = 0.f;
    #pragma unroll
    for (int k = 0; k < KNBR; ++k) { a[k] = expf(lg[k] - mx); s += a[k]; }
    float is = 1.0f / s;
    #pragma unroll
    for (int k = 0; k < KNBR; ++k) a[k] *= is;

    float vx = 0.f, vy = 0.f, vz = 0.f;
    #pragma unroll
    for (int k = 0; k < KNBR; ++k) {
        float gg = G[(size_t)jreg[k] * HEADS + h];
        float ag = a[k] * gg;
        vx += ag * unitL[w][k][0];
        vy += ag * unitL[w][k][1];
        vz += ag * unitL[w][k][2];
    }
    float vn = sqrtf(vx * vx + vy * vy + vz * vz + 1e-8f);

    float4 o0 = {0.f, 0.f, 0.f, 0.f}, o1 = {0.f, 0.f, 0.f, 0.f};
    #pragma unroll
    for (int k = 0; k < KNBR; ++k) {
        const float4* vp = (const float4*)(QKV + (size_t)jreg[k] * 1536 + 1024 + lane * 8);
        float4 v0 = vp[0], v1 = vp[1];
        float ak = a[k];
        o0.x += ak * v0.x; o0.y += ak * v0.y; o0.z += ak * v0.z; o0.w += ak * v0.w;
        o1.x += ak * v1.x; o1.y += ak * v1.y; o1.z += ak * v1.z; o1.w += ak * v1.w;
    }

    float ov[8] = {o0.x, o0.y, o0.z, o0.w, o1.x, o1.y, o1.z, o1.w};
    half8 hi8, lo8;
    #pragma unroll
    for (int t = 0; t < 8; ++t) {
        _Float16 hi = (_Float16)ov[t];
        hi8[t] = hi;
        lo8[t] = (_Float16)(ov[t] - (float)hi);
    }
    *(half8*)(att2 + (size_t)n * 1152 + lane * 8) = hi8;
    *(half8*)(att2 + (size_t)n * 1152 + 576 + lane * 8) = lo8;
    if (c == 0) {
        _Float16 hi = (_Float16)vn, lo = (_Float16)(vn - (float)hi);
        att2[(size_t)n * 1152 + 512 + h] = hi;
        att2[(size_t)n * 1152 + 576 + 512 + h] = lo;
    }
    if (lane < 56) {
        att2[(size_t)n * 1152 + 520 + lane] = (_Float16)0.f;
        att2[(size_t)n * 1152 + 1096 + lane] = (_Float16)0.f;
    }
}

// ---------------------------------------------------------------------------
// h2 = DynTanh(concat(h, x[:, :20])) -> split fp16 [N][1152], pads zeroed
// ---------------------------------------------------------------------------
__global__ void h2_split(const float* __restrict__ hh, const float* __restrict__ x,
                         const float* __restrict__ alpha2, const float* __restrict__ gamma2,
                         const float* __restrict__ beta2, _Float16* __restrict__ h2s) {
    int idx = blockIdx.x * 256 + threadIdx.x;      // n*576 + col
    if (idx >= NPTS * 576) return;
    int n = idx / 576, col = idx - n * 576;
    float v = 0.f;
    if (col < 532) {
        float s = (col < HIDD) ? hh[(size_t)n * HIDD + col]
                               : x[(size_t)n * CDIM + (col - HIDD)];
        v = tanhf(alpha2[0] * s) * gamma2[col] + beta2[col];
    }
    _Float16 hi = (_Float16)v, lo = (_Float16)(v - (float)hi);
    h2s[(size_t)n * 1152 + col] = hi;
    h2s[(size_t)n * 1152 + 576 + col] = lo;
}

// ---------------------------------------------------------------------------
// VQ: one wave per node (lane = codebook entry / output dim)
// ---------------------------------------------------------------------------
__launch_bounds__(256)
__global__ void vq_kernel(const float* __restrict__ z, const float* __restrict__ cb,
                          float* __restrict__ out, float* __restrict__ partials) {
    __shared__ float cbL[NEMB][65];
    __shared__ float zL[4][OUTD];
    __shared__ float psum[4];

    const int tid = threadIdx.x;
    for (int i = tid; i < NEMB * OUTD / 4; i += 256) {
        float4 v = ((const float4*)cb)[i];
        int e = (i * 4) >> 6;
        int c0 = (i * 4) & 63;
        cbL[e][c0 + 0] = v.x; cbL[e][c0 + 1] = v.y;
        cbL[e][c0 + 2] = v.z; cbL[e][c0 + 3] = v.w;
    }
    const int w = tid >> 6;
    const int lane = tid & 63;
    const int n = blockIdx.x * 4 + w;
    zL[w][lane] = z[(size_t)n * OUTD + lane];
    __syncthreads();

    float dot = 0.f, cc = 0.f;
    #pragma unroll
    for (int i = 0; i < OUTD; ++i) {
        float cv = cbL[lane][i];
        dot += zL[w][i] * cv;
        cc += cv * cv;
    }
    float best = cc - 2.f * dot;
    int bidx = lane;
    #pragma unroll
    for (int m = 1; m < 64; m <<= 1) {
        float ob = __shfl_xor(best, m, 64);
        int oi = __shfl_xor(bidx, m, 64);
        if (ob < best || (ob == best && oi < bidx)) { best = ob; bidx = oi; }
    }
    float zq = cbL[bidx][lane];
    out[(size_t)n * OUTD + lane] = zq;
    float diff = zL[w][lane] - zq;
    float sq = diff * diff;
    #pragma unroll
    for (int m = 1; m < 64; m <<= 1) sq += __shfl_xor(sq, m, 64);
    if (lane == 0) psum[w] = sq;
    __syncthreads();
    if (tid == 0) partials[blockIdx.x] = psum[0] + psum[1] + psum[2] + psum[3];
}

__global__ void vq_reduce(const float* __restrict__ partials, float* __restrict__ out) {
    __shared__ float s[256];
    int tid = threadIdx.x;
    float acc = 0.f;
    for (int i = tid; i < NPTS / 4; i += 256) acc += partials[i];
    s[tid] = acc;
    __syncthreads();
    for (int st = 128; st > 0; st >>= 1) {
        if (tid < st) s[tid] += s[tid + st];
        __syncthreads();
    }
    if (tid == 0) out[0] = 0.25f * s[0] / ((float)NPTS * (float)OUTD);
}

// ---------------------------------------------------------------------------
extern "C" void kernel_launch(void* const* d_in, const int* in_sizes, int n_in,
                              void* d_out, int out_size, void* d_ws, size_t ws_size,
                              hipStream_t stream) {
    const float* x      = (const float*)d_in[0];
    const float* coors  = (const float*)d_in[1];
    const int*   nbr    = (const int*)  d_in[2];
    const float* Wq     = (const float*)d_in[3];
    const float* Wk     = (const float*)d_in[4];
    const float* Wv     = (const float*)d_in[5];
    const float* w_gate = (const float*)d_in[6];
    const float* Wr1    = (const float*)d_in[7];
    const float* br1    = (const float*)d_in[8];
    const float* Wr2    = (const float*)d_in[9];
    const float* br2    = (const float*)d_in[10];
    const float* Wo     = (const float*)d_in[11];
    const float* alpha1 = (const float*)d_in[12];
    const float* gamma1 = (const float*)d_in[13];
    const float* beta1  = (const float*)d_in[14];
    const float* Wlin   = (const float*)d_in[15];
    const float* blin   = (const float*)d_in[16];
    const float* alpha2 = (const float*)d_in[17];
    const float* gamma2 = (const float*)d_in[18];
    const float* beta2  = (const float*)d_in[19];
    const float* Wout   = (const float*)d_in[20];
    const float* bout   = (const float*)d_in[21];
    const float* cb     = (const float*)d_in[22];

    char* wsb = (char*)d_ws;
    // byte offsets (peak ~151.4 MB); aliases noted
    _Float16* x2    = (_Float16*)(wsb + 0);          // 16 MB, dead after QKV gemm
    _Float16* wqkv2 = (_Float16*)(wsb + 16777216);   // 1.5 MB
    _Float16* wo2   = (_Float16*)(wsb + 18350080);   // 0.6 MB
    _Float16* wlin2 = (_Float16*)(wsb + 18939904);   // 0.5 MB
    _Float16* wout2 = (_Float16*)(wsb + 19464192);   // 0.3 MB
    float*    G     = (float*)   (wsb + 19759104);   // 0.5 MB
    float*    part  = (float*)   (wsb + 20283392);   // 16 KB
    float*    QKV   = (float*)   (wsb + 20299776);   // 100.7 MB, dead after attn
    _Float16* att2  = (_Float16*)(wsb + 120963072);  // 37.7 MB, dead after Wo gemm
    _Float16* h1s   = (_Float16*)(wsb + 0);          // alias x2 (16 MB)
    float*    hh    = (float*)   (wsb + 20299776);   // alias QKV (33.6 MB)
    _Float16* h2s   = (_Float16*)(wsb + 120963072);  // alias att2 (37.7 MB)
    float*    z     = (float*)   (wsb + 53854208);   // alias QKV tail (4.2 MB)

    float* outZ    = (float*)d_out;
    float* outLoss = outZ + (size_t)NPTS * OUTD;

    dim3 blk(256);

    // conversions
    x_split   <<<dim3(NPTS * CDIM / 256), blk, 0, stream>>>(x, x2);
    wqkv_split<<<dim3(1536 * 256 / 256), blk, 0, stream>>>(Wq, Wk, Wv, wqkv2);
    wT_split  <<<dim3(256 * 576 / 256), blk, 0, stream>>>(Wo,   wo2,   520, 256, 576, 256);
    wT_split  <<<dim3(512 * 256 / 256), blk, 0, stream>>>(Wlin, wlin2, 256, 512, 256, 512);
    wT_split  <<<dim3(128 * 576 / 256), blk, 0, stream>>>(Wout, wout2, 532, 64,  576, 128);
    gate_kernel<<<dim3(NPTS * HEADS / 256), blk, 0, stream>>>(x, w_gate, G);

    // QKV = x @ [Wq|Wk|Wv]   (fp32 out for attention)
    gemm_split<0><<<dim3(12, 128), blk, 0, stream>>>(x2, wqkv2, 256, 12, QKV, 1536,
                                                     nullptr, nullptr, nullptr, nullptr, nullptr);
    // attention -> att2 split
    attn_kernel<<<dim3(NPTS / 4), blk, 0, stream>>>(QKV, G, coors, nbr, Wr1, br1, Wr2, br2, att2);
    // h1 = DynTanh(x + att@Wo) -> split
    gemm_split<1><<<dim3(2, 128), blk, 0, stream>>>(att2, wo2, 576, 27, h1s, 0,
                                                    nullptr, x, alpha1, gamma1, beta1);
    // hh = gelu(h1@Wlin + blin) -> fp32
    gemm_split<2><<<dim3(4, 128), blk, 0, stream>>>(h1s, wlin2, 256, 12, hh, 512,
                                                    blin, nullptr, nullptr, nullptr, nullptr);
    // h2 = DynTanh(concat(hh, x[:,:20])) -> split
    h2_split<<<dim3(NPTS * 576 / 256), blk, 0, stream>>>(hh, x, alpha2, gamma2, beta2, h2s);
    // z = tanh(gelu(h2@Wout + bout)) -> fp32
    gemm_split<3><<<dim3(1, 128), blk, 0, stream>>>(h2s, wout2, 576, 27, z, 64,
                                                    bout, nullptr, nullptr, nullptr, nullptr);
    // VQ
    vq_kernel<<<dim3(NPTS / 4), blk, 0, stream>>>(z, cb, outZ, part);
    vq_reduce<<<dim3(1), blk, 0, stream>>>(part, outLoss);
}